// Round 7
// baseline (3726.325 us; speedup 1.0000x reference)
//
#include <hip/hip_runtime.h>

// VQ-VAE Vector Quantizer: N=65536 rows, K=4096 codes, D=64, fp32.
// R7: LDS-broadcast e-path + 2 rows/thread. ds_read (unlike SMEM s_load)
// supports fine-grained lgkmcnt pipelining; sharing each ds_read_b128 across
// 2 rows puts the per-code budget at 16 DS reads vs 128 FMA instrs (256
// issue-cyc) -> VALU cap ~90% (R2's 1-row version was 16:64 -> the measured
// 50% cap). __launch_bounds__(256,3): ~168 VGPR, 3 waves/SIMD, grid
// 128x6 = 768 blocks = exactly 3 blocks/CU, single residency round.
// S=6 uneven K-slices via computed bounds (682/683), ascending within and
// across slices -> first-index tie-break preserved.
// Per-row FMA chains bit-identical to R2-R6 passing kernels (quad-split
// partials by d mod 4, ascending d, (s0+s1)+(s2+s3),
// dist = fmaf(-2, dot, z2+e2[k])) => identical indices, absmax 0.
//
// out layout (float): [0,N*D) z_q_st | [ND] vq | [ND+1] cb | [ND+2] cm |
//                     [ND+3, ND+3+N) indices | [ND+3+N] perplexity | [ND+4+N] active

constexpr int N = 65536;
constexpr int K = 4096;
constexpr int D = 64;
constexpr int S = 6;       // K-split: grid = (N/512, 6) = 768 blocks = 3/CU exactly
constexpr int TK = 128;    // codes per LDS tile (32 KB)

__global__ __launch_bounds__(256) void prep_kernel(const float* __restrict__ emb,
                                                   float* __restrict__ e2,
                                                   int* __restrict__ counts,
                                                   float* __restrict__ loss) {
  int k = blockIdx.x * 256 + threadIdx.x;
  if (k < K) {
    const float4* ep = (const float4*)(emb + (size_t)k * D);
    float s0 = 0.f, s1 = 0.f, s2 = 0.f, s3 = 0.f;
#pragma unroll
    for (int i = 0; i < 16; ++i) {
      float4 e = ep[i];
      s0 = fmaf(e.x, e.x, s0);
      s1 = fmaf(e.y, e.y, s1);
      s2 = fmaf(e.z, e.z, s2);
      s3 = fmaf(e.w, e.w, s3);
    }
    e2[k] = (s0 + s1) + (s2 + s3);
    counts[k] = 0;
  }
  if (blockIdx.x == 0 && threadIdx.x == 0) *loss = 0.0f;
}

// Scan one K-slice, 2 rows per thread (rows blk*512+tid and +256).
// grid = (N/512, S). e staged in LDS, broadcast ds_read shared by both rows.
__global__ __launch_bounds__(256, 3) void vq_scan(const float* __restrict__ z,
                                                  const float* __restrict__ emb,
                                                  const float* __restrict__ e2,
                                                  float* __restrict__ pbest,
                                                  int* __restrict__ pidx) {
  __shared__ float lds_e[TK * D];   // 32 KB
  __shared__ float lds_e2[TK];

  const int tid = threadIdx.x;
  const int na = blockIdx.x * 512 + tid;        // row A
  const int nb = na + 256;                      // row B
  const int s = blockIdx.y;
  const int k0 = (s * K) / S;                   // computed slice bounds (uneven ok)
  const int kend = ((s + 1) * K) / S;

  // Two z rows in registers (128 floats).
  float4 zra[16], zrb[16];
  {
    const float4* zpa = (const float4*)(z + (size_t)na * D);
    const float4* zpb = (const float4*)(z + (size_t)nb * D);
#pragma unroll
    for (int i = 0; i < 16; ++i) { zra[i] = zpa[i]; zrb[i] = zpb[i]; }
  }

  // z2 per row, same instruction sequence as R2-R6 (quad-split, ascending d).
  float z2a, z2b;
  {
    float a0 = 0.f, a1 = 0.f, a2 = 0.f, a3 = 0.f;
    float b0 = 0.f, b1 = 0.f, b2 = 0.f, b3 = 0.f;
#pragma unroll
    for (int i = 0; i < 16; ++i) {
      a0 = fmaf(zra[i].x, zra[i].x, a0);
      a1 = fmaf(zra[i].y, zra[i].y, a1);
      a2 = fmaf(zra[i].z, zra[i].z, a2);
      a3 = fmaf(zra[i].w, zra[i].w, a3);
      b0 = fmaf(zrb[i].x, zrb[i].x, b0);
      b1 = fmaf(zrb[i].y, zrb[i].y, b1);
      b2 = fmaf(zrb[i].z, zrb[i].z, b2);
      b3 = fmaf(zrb[i].w, zrb[i].w, b3);
    }
    z2a = (a0 + a1) + (a2 + a3);
    z2b = (b0 + b1) + (b2 + b3);
  }

  float besta = 3.4e38f, bestb = 3.4e38f;
  int bidxa = k0, bidxb = k0;

  for (int kbase = k0; kbase < kend; kbase += TK) {
    const int tk = min(TK, kend - kbase);
    __syncthreads();
    {
      const float4* ep = (const float4*)(emb + (size_t)kbase * D);
      float4* lp = (float4*)lds_e;
      for (int i = tid; i < tk * 16; i += 256) lp[i] = ep[i];
      if (tid < tk) lds_e2[tid] = e2[kbase + tid];
    }
    __syncthreads();

#pragma unroll 2
    for (int k = 0; k < tk; ++k) {
      const float4* er = (const float4*)(lds_e + k * D);  // broadcast, conflict-free
      float a0 = 0.f, a1 = 0.f, a2 = 0.f, a3 = 0.f;
      float b0 = 0.f, b1 = 0.f, b2 = 0.f, b3 = 0.f;
#pragma unroll
      for (int i = 0; i < 16; ++i) {
        float4 e = er[i];   // one ds_read_b128 feeds both rows
        a0 = fmaf(zra[i].x, e.x, a0);
        a1 = fmaf(zra[i].y, e.y, a1);
        a2 = fmaf(zra[i].z, e.z, a2);
        a3 = fmaf(zra[i].w, e.w, a3);
        b0 = fmaf(zrb[i].x, e.x, b0);
        b1 = fmaf(zrb[i].y, e.y, b1);
        b2 = fmaf(zrb[i].z, e.z, b2);
        b3 = fmaf(zrb[i].w, e.w, b3);
      }
      float dota = (a0 + a1) + (a2 + a3);
      float dotb = (b0 + b1) + (b2 + b3);
      float ek2 = lds_e2[k];
      // == (z2 + e2[k]) - 2.0f*dot bitwise (2*dot exact, single rounding)
      float dista = fmaf(-2.0f, dota, z2a + ek2);
      float distb = fmaf(-2.0f, dotb, z2b + ek2);
      int kk = kbase + k;
      if (dista < besta) { besta = dista; bidxa = kk; }  // strict <: first-index
      if (distb < bestb) { bestb = distb; bidxb = kk; }
    }
  }

  pbest[(size_t)s * N + na] = besta;
  pidx[(size_t)s * N + na] = bidxa;
  pbest[(size_t)s * N + nb] = bestb;
  pidx[(size_t)s * N + nb] = bidxb;
}

// Combine slices (ascending s = ascending k => first-index tie-break preserved),
// then gather/losses/counts/index write.
__global__ __launch_bounds__(256) void vq_epilogue(const float* __restrict__ z,
                                                   const float* __restrict__ emb,
                                                   const float* __restrict__ pbest,
                                                   const int* __restrict__ pidx,
                                                   float* __restrict__ out,
                                                   int* __restrict__ counts,
                                                   float* __restrict__ loss) {
  __shared__ float red[4];
  const int tid = threadIdx.x;
  const int n = blockIdx.x * 256 + tid;

  float best = pbest[n];
  int bidx = pidx[n];
#pragma unroll
  for (int s = 1; s < S; ++s) {
    float d = pbest[(size_t)s * N + n];
    if (d < best) { best = d; bidx = pidx[(size_t)s * N + n]; }
  }

  out[(size_t)N * D + 3 + n] = (float)bidx;
  atomicAdd(&counts[bidx], 1);

  const float4* zp = (const float4*)(z + (size_t)n * D);
  const float4* qp = (const float4*)(emb + (size_t)bidx * D);
  float4* op = (float4*)(out + (size_t)n * D);
  float lsum = 0.f;
#pragma unroll
  for (int i = 0; i < 16; ++i) {
    float4 q = qp[i];
    float4 zz = zp[i];
    float dx = q.x - zz.x, dy = q.y - zz.y, dz = q.z - zz.z, dw = q.w - zz.w;
    lsum = fmaf(dx, dx, lsum);
    lsum = fmaf(dy, dy, lsum);
    lsum = fmaf(dz, dz, lsum);
    lsum = fmaf(dw, dw, lsum);
    // z_q_st = z + (z_q - z), replicated op-for-op
    float4 r;
    r.x = zz.x + dx; r.y = zz.y + dy; r.z = zz.z + dz; r.w = zz.w + dw;
    op[i] = r;
  }

#pragma unroll
  for (int off = 32; off > 0; off >>= 1) lsum += __shfl_down(lsum, off);
  if ((tid & 63) == 0) red[tid >> 6] = lsum;
  __syncthreads();
  if (tid == 0) atomicAdd(loss, (red[0] + red[1]) + (red[2] + red[3]));
}

__global__ __launch_bounds__(256) void finalize_kernel(const int* __restrict__ counts,
                                                       const float* __restrict__ loss,
                                                       float* __restrict__ out) {
  const int tid = threadIdx.x;
  double ent = 0.0;
  int active = 0;
  for (int k = tid; k < K; k += 256) {
    int c = counts[k];
    float p = (float)c / 65536.0f;
    if (c > 0) active++;
    ent += (double)(p * logf(p + 1e-10f));
  }
#pragma unroll
  for (int off = 32; off > 0; off >>= 1) {
    ent += __shfl_down(ent, off);
    active += __shfl_down(active, off);
  }
  __shared__ double ered[4];
  __shared__ int ared[4];
  if ((tid & 63) == 0) { ered[tid >> 6] = ent; ared[tid >> 6] = active; }
  __syncthreads();
  if (tid == 0) {
    double e = (ered[0] + ered[1]) + (ered[2] + ered[3]);
    int a = (ared[0] + ared[1]) + (ared[2] + ared[3]);
    float mean = *loss / (float)((size_t)N * D);
    float cb = mean;
    float cm = mean;
    float vq = cb + 0.25f * cm;
    size_t base = (size_t)N * D;
    out[base + 0] = vq;
    out[base + 1] = cb;
    out[base + 2] = cm;
    out[base + 3 + N] = (float)exp(-e);
    out[base + 4 + N] = (float)a;
  }
}

extern "C" void kernel_launch(void* const* d_in, const int* in_sizes, int n_in,
                              void* d_out, int out_size, void* d_ws, size_t ws_size,
                              hipStream_t stream) {
  const float* z = (const float*)d_in[0];
  const float* emb = (const float*)d_in[1];
  float* out = (float*)d_out;

  char* w = (char*)d_ws;
  float* e2 = (float*)w;                         w += (size_t)K * sizeof(float);
  int* counts = (int*)w;                         w += (size_t)K * sizeof(int);
  float* loss = (float*)w;                       w += 256;  // keep alignment
  float* pbest = (float*)w;                      w += (size_t)S * N * sizeof(float);
  int* pidx = (int*)w;

  prep_kernel<<<K / 256, 256, 0, stream>>>(emb, e2, counts, loss);
  vq_scan<<<dim3(N / 512, S), 256, 0, stream>>>(z, emb, e2, pbest, pidx);
  vq_epilogue<<<N / 256, 256, 0, stream>>>(z, emb, pbest, pidx, out, counts, loss);
  finalize_kernel<<<1, 256, 0, stream>>>(counts, loss, out);
}

// Round 8
// 2547.578 us; speedup vs baseline: 1.4627x; 1.4627x over previous
//
#include <hip/hip_runtime.h>

// VQ-VAE Vector Quantizer: N=65536, K=4096, D=64, fp32.
// R8: bf16-MFMA screening + exact fp32 rescore.
//   prep_e: e2 (bit-exact chain) + ebf (bf16 RNE)     prep_z: z2 + keymin init
//   vq_minscan  (MFMA): m[n] = min_k s_k,  s_k = fmaf(-2, dot_bf16, e2[k])
//   thr_kernel: thr[n] = m[n] + eps(n), eps = 7.7e-5*|z| + 4.1e-5  (sound bound:
//     |s_k - (dist_k - z2)| <= 2^-7*|z|*|e|max + 8e-6 ~= (eps/2.5)/2 per side)
//   vq_candscan (MFMA, identical bits): append (row,code) with s_k <= thr[row]
//   vq_rescore: exact fp32 chain (bit-identical to R1-R7 passing kernels),
//     atomicMin(key = dist_bits<<32 | k) -> min dist, tie -> min k (np argmin)
//   vq_epilogue / finalize: as in passing rounds.
// out layout (float): [0,N*D) z_q_st | [ND] vq | [ND+1] cb | [ND+2] cm |
//                     [ND+3,ND+3+N) indices | [ND+3+N] perplexity | [ND+4+N] active

constexpr int N = 65536;
constexpr int K = 4096;
constexpr int D = 64;
constexpr unsigned CAP = 6u * 65536u;

typedef short bf16x8 __attribute__((ext_vector_type(8)));
typedef float f32x4 __attribute__((ext_vector_type(4)));

__device__ inline unsigned short f2bf(float x) {  // RNE, no NaN inputs here
  unsigned u = __float_as_uint(x);
  return (unsigned short)((u + 0x7FFFu + ((u >> 16) & 1u)) >> 16);
}

__global__ __launch_bounds__(256) void prep_e(const float* __restrict__ emb,
                                              float* __restrict__ e2,
                                              unsigned short* __restrict__ ebf,
                                              int* __restrict__ counts,
                                              float* __restrict__ loss,
                                              unsigned* __restrict__ cnt) {
  int k = blockIdx.x * 256 + threadIdx.x;
  const float4* ep = (const float4*)(emb + (size_t)k * D);
  unsigned short* dst = ebf + (size_t)k * D;
  float s0 = 0.f, s1 = 0.f, s2 = 0.f, s3 = 0.f;
#pragma unroll
  for (int i = 0; i < 16; ++i) {
    float4 e = ep[i];
    s0 = fmaf(e.x, e.x, s0);
    s1 = fmaf(e.y, e.y, s1);
    s2 = fmaf(e.z, e.z, s2);
    s3 = fmaf(e.w, e.w, s3);
    dst[4 * i + 0] = f2bf(e.x);
    dst[4 * i + 1] = f2bf(e.y);
    dst[4 * i + 2] = f2bf(e.z);
    dst[4 * i + 3] = f2bf(e.w);
  }
  e2[k] = (s0 + s1) + (s2 + s3);  // bit-identical chain to R1-R7
  counts[k] = 0;
  if (k == 0) { *loss = 0.f; *cnt = 0u; }
}

__global__ __launch_bounds__(256) void prep_z(const float* __restrict__ z,
                                              float* __restrict__ z2,
                                              unsigned long long* __restrict__ keymin) {
  int n = blockIdx.x * 256 + threadIdx.x;
  const float4* zp = (const float4*)(z + (size_t)n * D);
  float s0 = 0.f, s1 = 0.f, s2 = 0.f, s3 = 0.f;
#pragma unroll
  for (int i = 0; i < 16; ++i) {
    float4 v = zp[i];
    s0 = fmaf(v.x, v.x, s0);
    s1 = fmaf(v.y, v.y, s1);
    s2 = fmaf(v.z, v.z, s2);
    s3 = fmaf(v.w, v.w, s3);
  }
  z2[n] = (s0 + s1) + (s2 + s3);  // bit-identical chain to R1-R7
  keymin[n] = 0xFFFFFFFFFFFFFFFFull;
}

// MFMA 16x16x32 bf16. A-frag: lane holds A[m=lane&15][k=(lane>>4)*8+j].
// B-frag (symmetric): B[k=(lane>>4)*8+j][n=lane&15] = e[n][k] -> contiguous row read.
// C/D: col=lane&15, row=(lane>>4)*4+reg  [HW-verified].
// Block: 512 threads = 8 waves x 16 rows = 128 rows. Grid N/128. No LDS.
__global__ __launch_bounds__(512) void vq_minscan(const float* __restrict__ z,
                                                  const unsigned short* __restrict__ ebf,
                                                  const float* __restrict__ e2,
                                                  float* __restrict__ m) {
  const int tid = threadIdx.x;
  const int lane = tid & 63;
  const int lcol = lane & 15;
  const int quad = lane >> 4;
  const int wv = tid >> 6;
  const int R0 = blockIdx.x * 128;

  const float* zrow = z + (size_t)(R0 + wv * 16 + lcol) * D;
  bf16x8 a0, a1;
#pragma unroll
  for (int j = 0; j < 8; ++j) a0[j] = (short)f2bf(zrow[quad * 8 + j]);
#pragma unroll
  for (int j = 0; j < 8; ++j) a1[j] = (short)f2bf(zrow[32 + quad * 8 + j]);

  float m0 = 3.4e38f, m1 = 3.4e38f, m2 = 3.4e38f, m3 = 3.4e38f;

#pragma unroll 2
  for (int ct = 0; ct < K / 16; ++ct) {
    int code = ct * 16 + lcol;
    const unsigned short* eb = ebf + (size_t)code * D + quad * 8;
    bf16x8 b0 = *(const bf16x8*)(eb);
    bf16x8 b1 = *(const bf16x8*)(eb + 32);
    float e2v = e2[code];
    f32x4 acc = {0.f, 0.f, 0.f, 0.f};
    acc = __builtin_amdgcn_mfma_f32_16x16x32_bf16(a0, b0, acc, 0, 0, 0);
    acc = __builtin_amdgcn_mfma_f32_16x16x32_bf16(a1, b1, acc, 0, 0, 0);
    m0 = fminf(m0, fmaf(-2.0f, acc[0], e2v));
    m1 = fminf(m1, fmaf(-2.0f, acc[1], e2v));
    m2 = fminf(m2, fmaf(-2.0f, acc[2], e2v));
    m3 = fminf(m3, fmaf(-2.0f, acc[3], e2v));
  }

  float mv[4] = {m0, m1, m2, m3};
#pragma unroll
  for (int r = 0; r < 4; ++r) {
    float v = mv[r];
    v = fminf(v, __shfl_xor(v, 1));
    v = fminf(v, __shfl_xor(v, 2));
    v = fminf(v, __shfl_xor(v, 4));
    v = fminf(v, __shfl_xor(v, 8));
    if (lcol == 0) m[R0 + wv * 16 + quad * 4 + r] = v;
  }
}

__global__ __launch_bounds__(256) void thr_kernel(const float* __restrict__ m,
                                                  const float* __restrict__ z2,
                                                  float* __restrict__ thr) {
  int n = blockIdx.x * 256 + threadIdx.x;
  thr[n] = m[n] + fmaf(sqrtf(z2[n]), 7.7e-5f, 4.1e-5f);
}

__global__ __launch_bounds__(512) void vq_candscan(const float* __restrict__ z,
                                                   const unsigned short* __restrict__ ebf,
                                                   const float* __restrict__ e2,
                                                   const float* __restrict__ thr,
                                                   unsigned* __restrict__ list,
                                                   unsigned* __restrict__ cnt) {
  const int tid = threadIdx.x;
  const int lane = tid & 63;
  const int lcol = lane & 15;
  const int quad = lane >> 4;
  const int wv = tid >> 6;
  const int R0 = blockIdx.x * 128;
  const int rb = R0 + wv * 16 + quad * 4;  // C-rows base for this lane

  const float* zrow = z + (size_t)(R0 + wv * 16 + lcol) * D;
  bf16x8 a0, a1;
#pragma unroll
  for (int j = 0; j < 8; ++j) a0[j] = (short)f2bf(zrow[quad * 8 + j]);
#pragma unroll
  for (int j = 0; j < 8; ++j) a1[j] = (short)f2bf(zrow[32 + quad * 8 + j]);

  float t0 = thr[rb + 0], t1 = thr[rb + 1], t2 = thr[rb + 2], t3 = thr[rb + 3];

#pragma unroll 2
  for (int ct = 0; ct < K / 16; ++ct) {
    int code = ct * 16 + lcol;
    const unsigned short* eb = ebf + (size_t)code * D + quad * 8;
    bf16x8 b0 = *(const bf16x8*)(eb);
    bf16x8 b1 = *(const bf16x8*)(eb + 32);
    float e2v = e2[code];
    f32x4 acc = {0.f, 0.f, 0.f, 0.f};
    acc = __builtin_amdgcn_mfma_f32_16x16x32_bf16(a0, b0, acc, 0, 0, 0);  // identical bits to minscan
    acc = __builtin_amdgcn_mfma_f32_16x16x32_bf16(a1, b1, acc, 0, 0, 0);
    float s0 = fmaf(-2.0f, acc[0], e2v);
    float s1 = fmaf(-2.0f, acc[1], e2v);
    float s2 = fmaf(-2.0f, acc[2], e2v);
    float s3 = fmaf(-2.0f, acc[3], e2v);
    if (s0 <= t0) { unsigned i = atomicAdd(cnt, 1u); if (i < CAP) list[i] = ((unsigned)(rb + 0) << 12) | (unsigned)code; }
    if (s1 <= t1) { unsigned i = atomicAdd(cnt, 1u); if (i < CAP) list[i] = ((unsigned)(rb + 1) << 12) | (unsigned)code; }
    if (s2 <= t2) { unsigned i = atomicAdd(cnt, 1u); if (i < CAP) list[i] = ((unsigned)(rb + 2) << 12) | (unsigned)code; }
    if (s3 <= t3) { unsigned i = atomicAdd(cnt, 1u); if (i < CAP) list[i] = ((unsigned)(rb + 3) << 12) | (unsigned)code; }
  }
}

__global__ __launch_bounds__(256) void vq_rescore(const float* __restrict__ z,
                                                  const float* __restrict__ emb,
                                                  const float* __restrict__ e2,
                                                  const float* __restrict__ z2,
                                                  const unsigned* __restrict__ list,
                                                  const unsigned* __restrict__ cnt,
                                                  unsigned long long* __restrict__ keymin) {
  unsigned total = *cnt;
  if (total > CAP) total = CAP;
  for (unsigned i = blockIdx.x * 256 + threadIdx.x; i < total; i += gridDim.x * 256) {
    unsigned pc = list[i];
    int n = (int)(pc >> 12);
    int k = (int)(pc & 0xFFFu);
    const float4* zp = (const float4*)(z + (size_t)n * D);
    const float4* ep = (const float4*)(emb + (size_t)k * D);
    float s0 = 0.f, s1 = 0.f, s2 = 0.f, s3 = 0.f;
#pragma unroll
    for (int j = 0; j < 16; ++j) {
      float4 zz = zp[j];
      float4 ee = ep[j];
      s0 = fmaf(zz.x, ee.x, s0);
      s1 = fmaf(zz.y, ee.y, s1);
      s2 = fmaf(zz.z, ee.z, s2);
      s3 = fmaf(zz.w, ee.w, s3);
    }
    float dot = (s0 + s1) + (s2 + s3);
    // bit-identical to R1-R7: dist = (z2 + e2[k]) - 2*dot (fmaf form, exact 2x)
    float dist = fmaf(-2.0f, dot, z2[n] + e2[k]);
    unsigned long long key = ((unsigned long long)__float_as_uint(dist) << 32) | (unsigned)k;
    atomicMin(&keymin[n], key);  // dist>0 -> bit-monotone; tie -> min k = first index
  }
}

__global__ __launch_bounds__(256) void vq_epilogue(const float* __restrict__ z,
                                                   const float* __restrict__ emb,
                                                   const unsigned long long* __restrict__ keymin,
                                                   float* __restrict__ out,
                                                   int* __restrict__ counts,
                                                   float* __restrict__ loss) {
  __shared__ float red[4];
  const int tid = threadIdx.x;
  const int n = blockIdx.x * 256 + tid;

  int bidx = (int)(keymin[n] & 0xFFFull);
  out[(size_t)N * D + 3 + n] = (float)bidx;
  atomicAdd(&counts[bidx], 1);

  const float4* zp = (const float4*)(z + (size_t)n * D);
  const float4* qp = (const float4*)(emb + (size_t)bidx * D);
  float4* op = (float4*)(out + (size_t)n * D);
  float lsum = 0.f;
#pragma unroll
  for (int i = 0; i < 16; ++i) {
    float4 q = qp[i];
    float4 zz = zp[i];
    float dx = q.x - zz.x, dy = q.y - zz.y, dz = q.z - zz.z, dw = q.w - zz.w;
    lsum = fmaf(dx, dx, lsum);
    lsum = fmaf(dy, dy, lsum);
    lsum = fmaf(dz, dz, lsum);
    lsum = fmaf(dw, dw, lsum);
    float4 r;  // z_q_st = z + (z_q - z), op-for-op
    r.x = zz.x + dx; r.y = zz.y + dy; r.z = zz.z + dz; r.w = zz.w + dw;
    op[i] = r;
  }

#pragma unroll
  for (int off = 32; off > 0; off >>= 1) lsum += __shfl_down(lsum, off);
  if ((tid & 63) == 0) red[tid >> 6] = lsum;
  __syncthreads();
  if (tid == 0) atomicAdd(loss, (red[0] + red[1]) + (red[2] + red[3]));
}

__global__ __launch_bounds__(256) void finalize_kernel(const int* __restrict__ counts,
                                                       const float* __restrict__ loss,
                                                       float* __restrict__ out) {
  const int tid = threadIdx.x;
  double ent = 0.0;
  int active = 0;
  for (int k = tid; k < K; k += 256) {
    int c = counts[k];
    float p = (float)c / 65536.0f;
    if (c > 0) active++;
    ent += (double)(p * logf(p + 1e-10f));
  }
#pragma unroll
  for (int off = 32; off > 0; off >>= 1) {
    ent += __shfl_down(ent, off);
    active += __shfl_down(active, off);
  }
  __shared__ double ered[4];
  __shared__ int ared[4];
  if ((tid & 63) == 0) { ered[tid >> 6] = ent; ared[tid >> 6] = active; }
  __syncthreads();
  if (tid == 0) {
    double e = (ered[0] + ered[1]) + (ered[2] + ered[3]);
    int a = (ared[0] + ared[1]) + (ared[2] + ared[3]);
    float mean = *loss / (float)((size_t)N * D);
    float vq = mean + 0.25f * mean;
    size_t base = (size_t)N * D;
    out[base + 0] = vq;
    out[base + 1] = mean;
    out[base + 2] = mean;
    out[base + 3 + N] = (float)exp(-e);
    out[base + 4 + N] = (float)a;
  }
}

extern "C" void kernel_launch(void* const* d_in, const int* in_sizes, int n_in,
                              void* d_out, int out_size, void* d_ws, size_t ws_size,
                              hipStream_t stream) {
  const float* z = (const float*)d_in[0];
  const float* emb = (const float*)d_in[1];
  float* out = (float*)d_out;

  char* w = (char*)d_ws;
  unsigned long long* keymin = (unsigned long long*)w; w += (size_t)N * 8;
  float* e2 = (float*)w;                               w += (size_t)K * 4;
  float* z2 = (float*)w;                               w += (size_t)N * 4;
  float* m = (float*)w;                                w += (size_t)N * 4;
  float* thr = (float*)w;                              w += (size_t)N * 4;
  unsigned short* ebf = (unsigned short*)w;            w += (size_t)K * D * 2;
  unsigned* list = (unsigned*)w;                       w += (size_t)CAP * 4;
  int* counts = (int*)w;                               w += (size_t)K * 4;
  float* loss = (float*)w;                             w += 64;
  unsigned* cnt = (unsigned*)w;

  prep_e<<<K / 256, 256, 0, stream>>>(emb, e2, ebf, counts, loss, cnt);
  prep_z<<<N / 256, 256, 0, stream>>>(z, z2, keymin);
  vq_minscan<<<N / 128, 512, 0, stream>>>(z, ebf, e2, m);
  thr_kernel<<<N / 256, 256, 0, stream>>>(m, z2, thr);
  vq_candscan<<<N / 128, 512, 0, stream>>>(z, ebf, e2, thr, list, cnt);
  vq_rescore<<<512, 256, 0, stream>>>(z, emb, e2, z2, list, cnt, keymin);
  vq_epilogue<<<N / 256, 256, 0, stream>>>(z, emb, keymin, out, counts, loss);
  finalize_kernel<<<1, 256, 0, stream>>>(counts, loss, out);
}